// Round 6
// baseline (189.659 us; speedup 1.0000x reference)
//
#include <hip/hip_runtime.h>
#include <hip/hip_bf16.h>
#include <cmath>
#include <cstdint>

#define V_   10000
#define D_   300
#define P_   100
#define B_   32
#define T_   2048
#define NC_  2
#define CP_  450      // packed used cols: sum_p e(p), e = 3+p/25
#define CPAD 456      // padded packed-col stride (57 groups of 8, 16B aligned)

__device__ __constant__ int PS_[9] = {0, 13, 26, 38, 51, 63, 76, 88, 100};

// packed col -> original diag/bias/wc row (p*6 + i)
__device__ __forceinline__ int maprow(int c) {
    if (c < 75)  return (c / 3) * 6 + c % 3;
    if (c < 175) { int q = c - 75;  return (25 + q / 4) * 6 + q % 4; }
    if (c < 300) { int q = c - 175; return (50 + q / 5) * 6 + q % 5; }
    int q = c - 300; return (75 + q / 6) * 6 + q % 6;
}
// first packed col of pattern p
__device__ __forceinline__ int cstart(int p) {
    if (p < 25) return 3 * p;
    if (p < 50) return 75 + 4 * (p - 25);
    if (p < 75) return 175 + 5 * (p - 50);
    return 300 + 6 * (p - 75);
}
// monotone float<->uint for exact deterministic atomicMax
__device__ __forceinline__ uint32_t fkey(float v) {
    uint32_t u = __float_as_uint(v);
    return (u & 0x80000000u) ? ~u : (u | 0x80000000u);
}
__device__ __forceinline__ float fdec(uint32_t k) {
    uint32_t u = (k & 0x80000000u) ? (k ^ 0x80000000u) : ~k;
    return __uint_as_float(u);
}

__device__ __forceinline__ void load_lds16(const float* g, float* l) {
    __builtin_amdgcn_global_load_lds((const __attribute__((address_space(1))) void*)g,
                                     (__attribute__((address_space(3))) void*)l, 16, 0, 0);
}

// ---------------------------------------------------------------------------
// K0: build dT[d][cp] = diags[maprow(cp)][d], packed bias/wc, init scoresU.
// ---------------------------------------------------------------------------
__global__ __launch_bounds__(256) void k_tr(const float* __restrict__ diags,
                                            const float* __restrict__ bias,
                                            const float* __restrict__ wc,
                                            float* __restrict__ dT,
                                            float* __restrict__ bp,
                                            float* __restrict__ wp,
                                            uint32_t* __restrict__ scoresU) {
    const int idx = blockIdx.x * 256 + threadIdx.x;
    if (idx < B_ * P_) scoresU[idx] = 0x007FFFFFu;     // fkey(-inf)
    if (idx < CPAD) {
        float b = 0.f, w = 0.f;
        if (idx < CP_) { int r = maprow(idx); b = bias[r]; w = wc[r]; }
        bp[idx] = b; wp[idx] = w;
    }
    if (idx < D_ * CPAD) {
        const int d = idx / CPAD, cp = idx - d * CPAD;
        dT[idx] = (cp < CP_) ? diags[maprow(cp) * D_ + d] : 0.f;
    }
}

// ---------------------------------------------------------------------------
// K1: mt[v][cp] = max(dot + bias, wc). Tile 512v x 8c, 1140 blocks (~4.45/CU,
// LDS 40KB -> 4 blocks/CU). Wave = 128v x 8c; lane holds 2v (one ds_read_b64
// per dd, ~6cyc) vs 16 FMA (32cyc) -> VALU-bound per-pipe. All 4 waves share
// the c-group -> dT reads are block-uniform scalar loads (s-cache hits).
// Bijective XCD chunking keeps each XCD's emb slice (~1.5MB) L2-resident.
// ---------------------------------------------------------------------------
__global__ __launch_bounds__(256, 4) void k_gemm(const float* __restrict__ emb,
                                                 const float* __restrict__ dT,
                                                 const float* __restrict__ bp,
                                                 const float* __restrict__ wp,
                                                 float* __restrict__ mt) {
    __shared__ __align__(16) float embT[2][10][512];
    const int bid = blockIdx.x;                 // 1140 = 20 v-tiles x 57 c-tiles
    const int xcd = bid & 7, ii = bid >> 3;     // q=142, r=4 (m204 bijective)
    const int ord = (xcd < 4) ? (xcd * 143 + ii) : (572 + (xcd - 4) * 142 + ii);
    const int vt = ord / 57, ct = ord - vt * 57;
    const int v0 = vt * 512;
    const int cb = __builtin_amdgcn_readfirstlane(ct * 8);

    const int tid  = threadIdx.x;
    const int lane = tid & 63;
    const int wid  = tid >> 6;

    float acc[2][8] = {};

    auto stage = [&](int buf, int d0) {
        #pragma unroll
        for (int k = 0; k < 5; ++k) {
            const int u = wid + (k << 2);        // 0..19 instr-units
            const int r = u >> 1, hf = u & 1;
            int vsrc = v0 + (hf << 8) + (lane << 2);
            vsrc = min(vsrc, V_ - 4);            // tail clamp (masked at store)
            load_lds16(emb + (size_t)(d0 + r) * V_ + vsrc, &embT[buf][r][hf << 8]);
        }
    };

    stage(0, 0);
    __syncthreads();

    for (int ch = 0; ch < 30; ++ch) {
        if (ch < 29) stage((ch + 1) & 1, (ch + 1) * 10);  // async prefetch
        const int buf = ch & 1;
        #pragma unroll
        for (int dd = 0; dd < 10; ++dd) {
            const float2 ev = *(const float2*)&embT[buf][dd][(wid << 7) + (lane << 1)];
            const float* dr = dT + (size_t)(ch * 10 + dd) * CPAD + cb;   // uniform
            float dg[8];
            #pragma unroll
            for (int j = 0; j < 8; ++j) dg[j] = dr[j];
            #pragma unroll
            for (int j = 0; j < 8; ++j) {
                acc[0][j] = fmaf(ev.x, dg[j], acc[0][j]);
                acc[1][j] = fmaf(ev.y, dg[j], acc[1][j]);
            }
        }
        __syncthreads();   // drains prefetch vmcnt + protects buf reuse
    }

    float bs[8], ws2[8];
    #pragma unroll
    for (int j = 0; j < 8; ++j) { bs[j] = bp[cb + j]; ws2[j] = wp[cb + j]; }
    const int vbase = v0 + (wid << 7) + (lane << 1);
    #pragma unroll
    for (int i2 = 0; i2 < 2; ++i2) {
        const int v = vbase + i2;
        if (v < V_) {
            float4 o0, o1;
            o0.x = fmaxf(acc[i2][0] + bs[0], ws2[0]);
            o0.y = fmaxf(acc[i2][1] + bs[1], ws2[1]);
            o0.z = fmaxf(acc[i2][2] + bs[2], ws2[2]);
            o0.w = fmaxf(acc[i2][3] + bs[3], ws2[3]);
            o1.x = fmaxf(acc[i2][4] + bs[4], ws2[4]);
            o1.y = fmaxf(acc[i2][5] + bs[5], ws2[5]);
            o1.z = fmaxf(acc[i2][6] + bs[6], ws2[6]);
            o1.w = fmaxf(acc[i2][7] + bs[7], ws2[7]);
            *(float4*)&mt[(size_t)v * CPAD + cb]     = o0;
            *(float4*)&mt[(size_t)v * CPAD + cb + 4] = o1;
        }
    }
}

// ---------------------------------------------------------------------------
// K2: block = (b, 32 window-starts). Early-exit past doc_len. Stage needed
// token rows (450 cols, contiguous bursts, L3-resident) into LDS; compute
// window sums per pattern; width-32 shuffle max; deterministic atomicMax.
// ---------------------------------------------------------------------------
__global__ __launch_bounds__(256) void k_scan(const float* __restrict__ mt,
                                              const int* __restrict__ docs,
                                              const int* __restrict__ doc_lens,
                                              uint32_t* __restrict__ scoresU) {
    __shared__ float sm[37][453];      // odd stride -> conflict-free diagonals
    __shared__ int rowbuf[37];
    const int bid = blockIdx.x;        // 2048 = 64 ts x 32 b
    const int b = bid & 31, ts = bid >> 5;
    const int ts0 = ts * 32;
    const int len = doc_lens[b];
    if (ts0 + 3 > len) return;         // no valid window start in this segment
    const int tid = threadIdx.x;
    const int lane = tid & 63, wid = tid >> 6;
    const int nst = min(min(37, T_ - ts0), len - ts0);

    for (int q = tid; q < nst; q += 256) rowbuf[q] = docs[b * T_ + ts0 + q];
    __syncthreads();
    for (int r = wid; r < nst; r += 4) {
        const float* src = mt + (size_t)rowbuf[r] * CPAD;
        load_lds16(src + (lane << 2), &sm[r][0]);
        if (lane < 49) load_lds16(src + 256 + (lane << 2), &sm[r][256]);
    }
    __syncthreads();

    const int t = tid & 31;
    const int pset = tid >> 5;
    const int p0 = PS_[pset], p1 = PS_[pset + 1];
    for (int p = p0; p < p1; ++p) {
        const int e = 3 + p / 25;
        const int cb = cstart(p);
        float s = sm[t][cb];
        for (int i2 = 1; i2 < e; ++i2) s += sm[t + i2][cb + i2];
        float val = (ts0 + t + e <= len) ? s : -INFINITY;
        #pragma unroll
        for (int off = 16; off > 0; off >>= 1)
            val = fmaxf(val, __shfl_xor(val, off, 32));
        if (t == 0) atomicMax(&scoresU[b * P_ + p], fkey(val));
    }
}

// ---------------------------------------------------------------------------
// K3: decode keys, masked layernorm over P, binarize, linear.
// ---------------------------------------------------------------------------
__global__ __launch_bounds__(128) void k_final(const uint32_t* __restrict__ scoresU,
                                               const float* __restrict__ lw,
                                               const float* __restrict__ lb,
                                               float* __restrict__ out) {
    const int b = blockIdx.x;
    const int tid = threadIdx.x;
    __shared__ float sh[P_];
    __shared__ float stats[2];

    float s = 0.f;
    bool fin = false;
    if (tid < P_) {
        s = fdec(scoresU[b * P_ + tid]);
        fin = !isinf(s);
        sh[tid] = s;
    }
    __syncthreads();
    if (tid == 0) {
        int n = 0; float sum = 0.f;
        for (int p = 0; p < P_; p++) {
            float x = sh[p];
            if (!isinf(x)) { n++; sum += x; }
        }
        float mean = sum / (float)n;
        float var = 0.f;
        for (int p = 0; p < P_; p++) {
            float x = sh[p];
            if (!isinf(x)) { float d = x - mean; var += d * d; }
        }
        var /= (float)n;
        stats[0] = mean;
        stats[1] = 1.f / sqrtf(var + 1e-5f);
    }
    __syncthreads();
    if (tid < P_) {
        float norm = fin ? (s - stats[0]) * stats[1] : s;
        sh[tid] = (norm > 0.f) ? 1.f : 0.f;
    }
    __syncthreads();
    if (tid < NC_) {
        float accv = lb[tid];
        for (int p = 0; p < P_; p++) accv += sh[p] * lw[tid * P_ + p];
        out[b * NC_ + tid] = accv;
    }
}

extern "C" void kernel_launch(void* const* d_in, const int* in_sizes, int n_in,
                              void* d_out, int out_size, void* d_ws, size_t ws_size,
                              hipStream_t stream) {
    const float* emb   = (const float*)d_in[0];   // (300, 10000)
    const float* diags = (const float*)d_in[1];   // (600, 300)
    const float* bias  = (const float*)d_in[2];   // (600, 1)
    const float* wc    = (const float*)d_in[3];   // (100, 6)
    const float* lw    = (const float*)d_in[4];   // (2, 100)
    const float* lb    = (const float*)d_in[5];   // (2,)
    const int*   docs  = (const int*)d_in[6];     // (32, 2048)
    const int*   dlens = (const int*)d_in[7];     // (32,)
    float* out = (float*)d_out;                   // (32, 2)

    float*    mt      = (float*)d_ws;                               // 10000*456*4 = 18.24 MB
    float*    dT      = mt + (size_t)V_ * CPAD;                     // 300*456
    float*    bp      = dT + (size_t)D_ * CPAD;                     // 456
    float*    wp      = bp + CPAD;                                  // 456
    uint32_t* scoresU = (uint32_t*)(wp + CPAD);                     // 3200

    k_tr   <<<dim3(535),  256, 0, stream>>>(diags, bias, wc, dT, bp, wp, scoresU);
    k_gemm <<<dim3(1140), 256, 0, stream>>>(emb, dT, bp, wp, mt);
    k_scan <<<dim3(2048), 256, 0, stream>>>(mt, docs, dlens, scoresU);
    k_final<<<dim3(B_),   128, 0, stream>>>(scoresU, lw, lb, out);
}

// Round 7
// 184.814 us; speedup vs baseline: 1.0262x; 1.0262x over previous
//
#include <hip/hip_runtime.h>
#include <hip/hip_bf16.h>
#include <cmath>
#include <cstdint>

#define V_   10000
#define D_   300
#define P_   100
#define B_   32
#define T_   2048
#define NC_  2
#define CP_  450      // packed used cols: sum_p e(p), e = 3+p/25
#define CPAD 464      // 29 groups of 16 floats; every 16-group 64B-aligned

// scan pattern-groups: col starts (16B-aligned) and pattern ranges
__device__ __constant__ int G_c0[4] = {0, 124, 240, 348};
__device__ __constant__ int G_p0[5] = {0, 38, 63, 83, 100};

// packed col -> original diag/bias/wc row (p*6 + i)
__device__ __forceinline__ int maprow(int c) {
    if (c < 75)  return (c / 3) * 6 + c % 3;
    if (c < 175) { int q = c - 75;  return (25 + q / 4) * 6 + q % 4; }
    if (c < 300) { int q = c - 175; return (50 + q / 5) * 6 + q % 5; }
    int q = c - 300; return (75 + q / 6) * 6 + q % 6;
}
// first packed col of pattern p
__device__ __forceinline__ int cstart(int p) {
    if (p < 25) return 3 * p;
    if (p < 50) return 75 + 4 * (p - 25);
    if (p < 75) return 175 + 5 * (p - 50);
    return 300 + 6 * (p - 75);
}
// monotone float<->uint for exact deterministic atomicMax
__device__ __forceinline__ uint32_t fkey(float v) {
    uint32_t u = __float_as_uint(v);
    return (u & 0x80000000u) ? ~u : (u | 0x80000000u);
}
__device__ __forceinline__ float fdec(uint32_t k) {
    uint32_t u = (k & 0x80000000u) ? (k ^ 0x80000000u) : ~k;
    return __uint_as_float(u);
}

__device__ __forceinline__ void load_lds16(const float* g, float* l) {
    __builtin_amdgcn_global_load_lds((const __attribute__((address_space(1))) void*)g,
                                     (__attribute__((address_space(3))) void*)l, 16, 0, 0);
}

// ---------------------------------------------------------------------------
// K0: build dT[d][cp] = diags[maprow(cp)][d], packed bias/wc, init scoresU.
// ---------------------------------------------------------------------------
__global__ __launch_bounds__(256) void k_tr(const float* __restrict__ diags,
                                            const float* __restrict__ bias,
                                            const float* __restrict__ wc,
                                            float* __restrict__ dT,
                                            float* __restrict__ bp,
                                            float* __restrict__ wp,
                                            uint32_t* __restrict__ scoresU) {
    const int idx = blockIdx.x * 256 + threadIdx.x;
    if (idx < B_ * P_) scoresU[idx] = 0x007FFFFFu;     // fkey(-inf)
    if (idx < CPAD) {
        float b = 0.f, w = 0.f;
        if (idx < CP_) { int r = maprow(idx); b = bias[r]; w = wc[r]; }
        bp[idx] = b; wp[idx] = w;
    }
    if (idx < D_ * CPAD) {
        const int d = idx / CPAD, cp = idx - d * CPAD;
        dT[idx] = (cp < CP_) ? diags[maprow(cp) * D_ + d] : 0.f;
    }
}

// ---------------------------------------------------------------------------
// K1: mt[v][cp] = max(dot + bias, wc). NO LDS, NO barriers.
// Block = 256 lanes x 16 c. Lane owns one v column: per d, one coalesced
// global_load_dword (L2-resident emb slice via XCD chunking) + 16 FMAs whose
// second operand is an SGPR from s_load_dwordx16 of the uniform dT row slice.
// 1160 blocks = 8 XCDs x 145 (bijective chunking, ~1.5MB emb slice/XCD).
// ---------------------------------------------------------------------------
__global__ __launch_bounds__(256) void k_gemm(const float* __restrict__ emb,
                                              const float* __restrict__ dT,
                                              const float* __restrict__ bp,
                                              const float* __restrict__ wp,
                                              float* __restrict__ mt) {
    const int bid = blockIdx.x;            // 1160 = 40 v-tiles x 29 c-tiles
    const int xcd = bid & 7, ii = bid >> 3;
    const int ord = xcd * 145 + ii;        // q=145, r=0 -> exact bijection
    const int vt = ord / 29, ct = ord - vt * 29;
    const int cb = ct * 16;
    const int tid = threadIdx.x;
    const int v = vt * 256 + tid;
    const int vc = min(v, V_ - 1);         // tail clamp (store masked)

    const float* ep = emb + vc;
    const float* dr = dT + cb;

    float acc[16] = {};
    #pragma unroll 2
    for (int d = 0; d < D_; ++d) {
        const float ev = ep[(size_t)d * V_];
        const float* dg = dr + (size_t)d * CPAD;   // block-uniform -> s_load
        #pragma unroll
        for (int j = 0; j < 16; ++j)
            acc[j] = fmaf(ev, dg[j], acc[j]);
    }

    if (v < V_) {
        #pragma unroll
        for (int j = 0; j < 16; ++j)
            acc[j] = fmaxf(acc[j] + bp[cb + j], wp[cb + j]);
        float* op = mt + (size_t)v * CPAD + cb;
        #pragma unroll
        for (int q = 0; q < 4; ++q)
            *(float4*)(op + q * 4) = make_float4(acc[q*4], acc[q*4+1],
                                                 acc[q*4+2], acc[q*4+3]);
    }
}

// ---------------------------------------------------------------------------
// K2: block = (b, 64 window-starts, pattern-quarter). Stage 69 rows x 128
// cols (one 512B load_lds16 per row, 32 lanes) into 36KB LDS -> 4 blocks/CU.
// Wave w handles pattern subset p = G_p0[pg]+w step 4; lanes = 64 starts;
// width-64 shuffle max; deterministic atomicMax(uint-key).
// ---------------------------------------------------------------------------
#define SROW 69
#define SST  132

__global__ __launch_bounds__(256) void k_scan(const float* __restrict__ mt,
                                              const int* __restrict__ docs,
                                              const int* __restrict__ doc_lens,
                                              uint32_t* __restrict__ scoresU) {
    __shared__ float sm[SROW][SST];        // 36432 B
    __shared__ int rowbuf[SROW];
    const int bid = blockIdx.x;            // 4096 = 32b x 32ts x 4pg
    const int pg = bid & 3;
    const int ts = (bid >> 2) & 31;
    const int b  = bid >> 7;
    const int ts0 = ts * 64;
    const int len = doc_lens[b];
    if (ts0 + 3 > len) return;             // no valid window start here
    const int tid = threadIdx.x;
    const int lane = tid & 63, wid = tid >> 6;
    const int nst = min(SROW, min(T_ - ts0, len - ts0));
    const int c0 = G_c0[pg];

    for (int q = tid; q < nst; q += 256) rowbuf[q] = docs[b * T_ + ts0 + q];
    __syncthreads();
    for (int r = wid; r < nst; r += 4)
        if (lane < 32)
            load_lds16(mt + (size_t)rowbuf[r] * CPAD + c0 + (lane << 2), &sm[r][0]);
    __syncthreads();

    const int t = lane;                    // window start within segment
    for (int p = G_p0[pg] + wid; p < G_p0[pg + 1]; p += 4) {
        const int e = 3 + p / 25;          // wave-uniform
        const int cbs = cstart(p) - c0;
        float s = sm[t][cbs];
        for (int i = 1; i < e; ++i) s += sm[t + i][cbs + i];
        float val = (ts0 + t + e <= len) ? s : -INFINITY;
        #pragma unroll
        for (int off = 32; off > 0; off >>= 1)
            val = fmaxf(val, __shfl_xor(val, off, 64));
        if (lane == 0) atomicMax(&scoresU[b * P_ + p], fkey(val));
    }
}

// ---------------------------------------------------------------------------
// K3: decode keys, masked layernorm over P, binarize, linear.
// ---------------------------------------------------------------------------
__global__ __launch_bounds__(128) void k_final(const uint32_t* __restrict__ scoresU,
                                               const float* __restrict__ lw,
                                               const float* __restrict__ lb,
                                               float* __restrict__ out) {
    const int b = blockIdx.x;
    const int tid = threadIdx.x;
    __shared__ float sh[P_];
    __shared__ float stats[2];

    float s = 0.f;
    bool fin = false;
    if (tid < P_) {
        s = fdec(scoresU[b * P_ + tid]);
        fin = !isinf(s);
        sh[tid] = s;
    }
    __syncthreads();
    if (tid == 0) {
        int n = 0; float sum = 0.f;
        for (int p = 0; p < P_; p++) {
            float x = sh[p];
            if (!isinf(x)) { n++; sum += x; }
        }
        float mean = sum / (float)n;
        float var = 0.f;
        for (int p = 0; p < P_; p++) {
            float x = sh[p];
            if (!isinf(x)) { float d = x - mean; var += d * d; }
        }
        var /= (float)n;
        stats[0] = mean;
        stats[1] = 1.f / sqrtf(var + 1e-5f);
    }
    __syncthreads();
    if (tid < P_) {
        float norm = fin ? (s - stats[0]) * stats[1] : s;
        sh[tid] = (norm > 0.f) ? 1.f : 0.f;
    }
    __syncthreads();
    if (tid < NC_) {
        float accv = lb[tid];
        for (int p = 0; p < P_; p++) accv += sh[p] * lw[tid * P_ + p];
        out[b * NC_ + tid] = accv;
    }
}

extern "C" void kernel_launch(void* const* d_in, const int* in_sizes, int n_in,
                              void* d_out, int out_size, void* d_ws, size_t ws_size,
                              hipStream_t stream) {
    const float* emb   = (const float*)d_in[0];   // (300, 10000)
    const float* diags = (const float*)d_in[1];   // (600, 300)
    const float* bias  = (const float*)d_in[2];   // (600, 1)
    const float* wc    = (const float*)d_in[3];   // (100, 6)
    const float* lw    = (const float*)d_in[4];   // (2, 100)
    const float* lb    = (const float*)d_in[5];   // (2,)
    const int*   docs  = (const int*)d_in[6];     // (32, 2048)
    const int*   dlens = (const int*)d_in[7];     // (32,)
    float* out = (float*)d_out;                   // (32, 2)

    float*    mt      = (float*)d_ws;                               // 10000*464*4 = 18.56 MB
    float*    dT      = mt + (size_t)V_ * CPAD;                     // 300*464
    float*    bp      = dT + (size_t)D_ * CPAD;                     // 464
    float*    wp      = bp + CPAD;                                  // 464
    uint32_t* scoresU = (uint32_t*)(wp + CPAD);                     // 3200

    k_tr   <<<dim3(544),  256, 0, stream>>>(diags, bias, wc, dT, bp, wp, scoresU);
    k_gemm <<<dim3(1160), 256, 0, stream>>>(emb, dT, bp, wp, mt);
    k_scan <<<dim3(4096), 256, 0, stream>>>(mt, docs, dlens, scoresU);
    k_final<<<dim3(B_),   128, 0, stream>>>(scoresU, lw, lb, out);
}

// Round 8
// 165.506 us; speedup vs baseline: 1.1459x; 1.1167x over previous
//
#include <hip/hip_runtime.h>
#include <hip/hip_bf16.h>
#include <cmath>
#include <cstdint>

#define V_   10000
#define D_   300
#define P_   100
#define B_   32
#define T_   2048
#define NC_  2
#define CP_  450      // packed used cols: sum_p e(p), e = 3+p/25
#define CPAD 464      // 29 groups of 16 floats; every 16-group 64B-aligned

// scan pattern-groups: col starts (16B-aligned) and pattern ranges
__device__ __constant__ int G_c0[4] = {0, 124, 240, 348};
__device__ __constant__ int G_p0[5] = {0, 38, 63, 83, 100};

// packed col -> original diag/bias/wc row (p*6 + i)
__device__ __forceinline__ int maprow(int c) {
    if (c < 75)  return (c / 3) * 6 + c % 3;
    if (c < 175) { int q = c - 75;  return (25 + q / 4) * 6 + q % 4; }
    if (c < 300) { int q = c - 175; return (50 + q / 5) * 6 + q % 5; }
    int q = c - 300; return (75 + q / 6) * 6 + q % 6;
}
// first packed col of pattern p
__device__ __forceinline__ int cstart(int p) {
    if (p < 25) return 3 * p;
    if (p < 50) return 75 + 4 * (p - 25);
    if (p < 75) return 175 + 5 * (p - 50);
    return 300 + 6 * (p - 75);
}

__device__ __forceinline__ void load_lds16(const float* g, float* l) {
    __builtin_amdgcn_global_load_lds((const __attribute__((address_space(1))) void*)g,
                                     (__attribute__((address_space(3))) void*)l, 16, 0, 0);
}

// ---------------------------------------------------------------------------
// K0: build dT[d][cp] = diags[maprow(cp)][d], packed bias/wc.
// ---------------------------------------------------------------------------
__global__ __launch_bounds__(256) void k_tr(const float* __restrict__ diags,
                                            const float* __restrict__ bias,
                                            const float* __restrict__ wc,
                                            float* __restrict__ dT,
                                            float* __restrict__ bp,
                                            float* __restrict__ wp) {
    const int idx = blockIdx.x * 256 + threadIdx.x;
    if (idx < CPAD) {
        float b = 0.f, w = 0.f;
        if (idx < CP_) { int r = maprow(idx); b = bias[r]; w = wc[r]; }
        bp[idx] = b; wp[idx] = w;
    }
    if (idx < D_ * CPAD) {
        const int d = idx / CPAD, cp = idx - d * CPAD;
        dT[idx] = (cp < CP_) ? diags[maprow(cp) * D_ + d] : 0.f;
    }
}

// ---------------------------------------------------------------------------
// K1: mt[v][cp] = max(dot + bias, wc). NO LDS, NO barriers.
// Lane owns one v column; 6-deep double-buffered register pipeline of
// coalesced emb loads; 16 c coefficients arrive as SGPRs (uniform s_loads).
// 1160 blocks = 8 XCDs x 145 (bijective chunking, ~1.5MB emb slice/XCD).
// ---------------------------------------------------------------------------
__global__ __launch_bounds__(256) void k_gemm(const float* __restrict__ emb,
                                              const float* __restrict__ dT,
                                              const float* __restrict__ bp,
                                              const float* __restrict__ wp,
                                              float* __restrict__ mt) {
    const int bid = blockIdx.x;            // 1160 = 40 v-tiles x 29 c-tiles
    const int xcd = bid & 7, ii = bid >> 3;
    const int ord = xcd * 145 + ii;        // exact bijection (1160 = 8*145)
    const int vt = ord / 29, ct = ord - vt * 29;
    const int cb = ct * 16;
    const int tid = threadIdx.x;
    const int v = vt * 256 + tid;
    const int vc = min(v, V_ - 1);         // tail clamp (store masked)

    const float* ep = emb + vc;
    const float* dr = dT + cb;

    float acc[16] = {};
    float evA[6], evB[6];
    #pragma unroll
    for (int u = 0; u < 6; ++u) evA[u] = ep[(size_t)u * V_];

    #pragma unroll 2
    for (int g = 0; g < 50; ++g) {
        const int d0 = g * 6;
        if (g < 49) {
            #pragma unroll
            for (int u = 0; u < 6; ++u) evB[u] = ep[(size_t)(d0 + 6 + u) * V_];
        }
        #pragma unroll
        for (int u = 0; u < 6; ++u) {
            const float* dg = dr + (size_t)(d0 + u) * CPAD;   // uniform -> s_load
            #pragma unroll
            for (int j = 0; j < 16; ++j)
                acc[j] = fmaf(evA[u], dg[j], acc[j]);
        }
        #pragma unroll
        for (int u = 0; u < 6; ++u) evA[u] = evB[u];
    }

    if (v < V_) {
        #pragma unroll
        for (int j = 0; j < 16; ++j)
            acc[j] = fmaxf(acc[j] + bp[cb + j], wp[cb + j]);
        float* op = mt + (size_t)v * CPAD + cb;
        #pragma unroll
        for (int q = 0; q < 4; ++q)
            *(float4*)(op + q * 4) = make_float4(acc[q*4], acc[q*4+1],
                                                 acc[q*4+2], acc[q*4+3]);
    }
}

// ---------------------------------------------------------------------------
// K2: block = (b, 64 window-starts, pattern-quarter). Stage 69 rows x 128
// cols (512B load_lds16 per row, 32 lanes) into 36KB LDS -> 4 blocks/CU.
// Wave w handles patterns G_p0[pg]+w step 4; lanes = 64 starts; width-64
// shuffle max; per-block partial result -> part[] (no atomics).
// ---------------------------------------------------------------------------
#define SROW 69
#define SST  132

__global__ __launch_bounds__(256) void k_scan(const float* __restrict__ mt,
                                              const int* __restrict__ docs,
                                              const int* __restrict__ doc_lens,
                                              float* __restrict__ part) {
    __shared__ float sm[SROW][SST];        // 36432 B
    __shared__ int rowbuf[SROW];
    const int bid = blockIdx.x;            // 4096 = 32b x 32ts x 4pg
    const int pg = bid & 3;
    const int ts = (bid >> 2) & 31;
    const int b  = bid >> 7;
    const int ts0 = ts * 64;
    const int len = doc_lens[b];
    if (ts0 + 3 > len) return;             // invalid segment: k_final skips it
    const int tid = threadIdx.x;
    const int lane = tid & 63, wid = tid >> 6;
    const int nst = min(SROW, min(T_ - ts0, len - ts0));
    const int c0 = G_c0[pg];

    for (int q = tid; q < nst; q += 256) rowbuf[q] = docs[b * T_ + ts0 + q];
    __syncthreads();
    for (int r = wid; r < nst; r += 4)
        if (lane < 32)
            load_lds16(mt + (size_t)rowbuf[r] * CPAD + c0 + (lane << 2), &sm[r][0]);
    __syncthreads();

    const int t = lane;                    // window start within segment
    for (int p = G_p0[pg] + wid; p < G_p0[pg + 1]; p += 4) {
        const int e = 3 + p / 25;          // wave-uniform
        const int cbs = cstart(p) - c0;
        float s = sm[t][cbs];
        for (int i = 1; i < e; ++i) s += sm[t + i][cbs + i];
        float val = (ts0 + t + e <= len) ? s : -INFINITY;
        #pragma unroll
        for (int off = 32; off > 0; off >>= 1)
            val = fmaxf(val, __shfl_xor(val, off, 64));
        if (lane == 0) part[((size_t)b * 32 + ts) * P_ + p] = val;
    }
}

// ---------------------------------------------------------------------------
// K3: reduce valid segments, masked layernorm over P, binarize, linear.
// ---------------------------------------------------------------------------
__global__ __launch_bounds__(128) void k_final(const float* __restrict__ part,
                                               const int* __restrict__ doc_lens,
                                               const float* __restrict__ lw,
                                               const float* __restrict__ lb,
                                               float* __restrict__ out) {
    const int b = blockIdx.x;
    const int tid = threadIdx.x;
    __shared__ float sh[P_];
    __shared__ float stats[2];

    const int len = doc_lens[b];
    const int nseg = min(32, (len - 3) / 64 + 1);   // len >= T/2 always

    float s = -INFINITY;
    bool fin = false;
    if (tid < P_) {
        for (int sg = 0; sg < nseg; ++sg)
            s = fmaxf(s, part[((size_t)b * 32 + sg) * P_ + tid]);
        fin = !isinf(s);
        sh[tid] = s;
    }
    __syncthreads();
    if (tid == 0) {
        int n = 0; float sum = 0.f;
        for (int p = 0; p < P_; p++) {
            float x = sh[p];
            if (!isinf(x)) { n++; sum += x; }
        }
        float mean = sum / (float)n;
        float var = 0.f;
        for (int p = 0; p < P_; p++) {
            float x = sh[p];
            if (!isinf(x)) { float d = x - mean; var += d * d; }
        }
        var /= (float)n;
        stats[0] = mean;
        stats[1] = 1.f / sqrtf(var + 1e-5f);
    }
    __syncthreads();
    if (tid < P_) {
        float norm = fin ? (s - stats[0]) * stats[1] : s;
        sh[tid] = (norm > 0.f) ? 1.f : 0.f;
    }
    __syncthreads();
    if (tid < NC_) {
        float accv = lb[tid];
        for (int p = 0; p < P_; p++) accv += sh[p] * lw[tid * P_ + p];
        out[b * NC_ + tid] = accv;
    }
}

extern "C" void kernel_launch(void* const* d_in, const int* in_sizes, int n_in,
                              void* d_out, int out_size, void* d_ws, size_t ws_size,
                              hipStream_t stream) {
    const float* emb   = (const float*)d_in[0];   // (300, 10000)
    const float* diags = (const float*)d_in[1];   // (600, 300)
    const float* bias  = (const float*)d_in[2];   // (600, 1)
    const float* wc    = (const float*)d_in[3];   // (100, 6)
    const float* lw    = (const float*)d_in[4];   // (2, 100)
    const float* lb    = (const float*)d_in[5];   // (2,)
    const int*   docs  = (const int*)d_in[6];     // (32, 2048)
    const int*   dlens = (const int*)d_in[7];     // (32,)
    float* out = (float*)d_out;                   // (32, 2)

    float* mt   = (float*)d_ws;                               // 10000*464*4 = 18.56 MB
    float* dT   = mt + (size_t)V_ * CPAD;                     // 300*464
    float* bp   = dT + (size_t)D_ * CPAD;                     // 464
    float* wp   = bp + CPAD;                                  // 464
    float* part = wp + CPAD;                                  // 32*32*100 = 409.6 KB

    k_tr   <<<dim3(544),  256, 0, stream>>>(diags, bias, wc, dT, bp, wp);
    k_gemm <<<dim3(1160), 256, 0, stream>>>(emb, dT, bp, wp, mt);
    k_scan <<<dim3(4096), 256, 0, stream>>>(mt, docs, dlens, part);
    k_final<<<dim3(B_),   128, 0, stream>>>(part, dlens, lw, lb, out);
}